// Round 3
// baseline (661.660 us; speedup 1.0000x reference)
//
#include <hip/hip_runtime.h>

// VectorQuantizer: x[16384][64] fp32, codebook[8192][64] fp32
// out = concat(discrete one-hot [16384][8192] fp32, quantized [16384][64] fp32)
// argmin_k ||x-c_k||^2 == argmax_k (x.c_k - 0.5||c_k||^2)
//
// r15 -> r16: SPLIT the one-hot zero-fill out of the compute kernel.
// r13 (interleaved NT stores) = 531us, r14 (occupancy) = 541, r15 (phase
// blast) = 578 -> the fused loop never reaches fill-rate write BW; it pays
// ~180us against a ~90us store floor. New structure:
//   k_zero: dedicated NT zero-fill of the 536 MB one-hot region, same
//           shape as the harness's own fillBuffer (measured 6.2 TB/s).
//   k_main: r13 compute loop with ALL stores removed from the hot loop --
//           pure L2 loads + MFMA, paced at ~20-30us; writes only the 32
//           one-hot 1.0s + quantized rows at the end.
// Stream order guarantees k_zero completes before k_main's 1.0 writes.
// Exact fp32 dots via fp16 hi/lo split, 16 MFMA terms, bit-identical order.

#define NROWS 16384
#define KCODES 8192
#define DDIM 64
#define RPB 32                    // rows per block
#define CWAVES 4                  // waves per block (256 threads)
#define WCODES (KCODES / CWAVES)  // 2048 codes per wave
#define WTILES (WCODES / 16)      // 128 tiles per wave

typedef float    f32x4 __attribute__((ext_vector_type(4)));
typedef _Float16 f16x8 __attribute__((ext_vector_type(8)));

// ---------------- kernel 0: fused pack + cn2 ----------------
// thread (Tg, L): code = Tg*16 + (L&15), k-slice = (L>>4)*8 (+32).
// packed[Tg][frag][lane]: frag 0=hi k0..31, 1=hi k32..63, 2=lo k0..31, 3=lo k32..63.
__global__ __launch_bounds__(256) void k_prep(const float* __restrict__ cb,
                                              f16x8* __restrict__ packed,
                                              float* __restrict__ cn2) {
    int tid = blockIdx.x * 256 + threadIdx.x;   // 0..32767
    int Tg = tid >> 6, L = tid & 63;
    int lane15 = L & 15, quad = L >> 4;
    int code = Tg * 16 + lane15;
    const float* p = cb + (size_t)code * DDIM + quad * 8;
    f16x8 h0, l0, h1, l1;
    float s = 0.f;
#pragma unroll
    for (int j = 0; j < 8; ++j) {
        float v = p[j];
        _Float16 h = (_Float16)v;
        h0[j] = h; l0[j] = (_Float16)(v - (float)h);
        s = fmaf(v, v, s);
        float w = p[32 + j];
        _Float16 h2 = (_Float16)w;
        h1[j] = h2; l1[j] = (_Float16)(w - (float)h2);
        s = fmaf(w, w, s);
    }
    s += __shfl_xor(s, 16, 64);
    s += __shfl_xor(s, 32, 64);
    if (quad == 0) cn2[code] = 0.5f * s;
    f16x8* out = packed + (size_t)Tg * 256 + L;
    out[0]   = h0;
    out[64]  = h1;
    out[128] = l0;
    out[192] = l1;
}

// ---------------- kernel 1: dedicated NT zero-fill of the one-hot region ----------------
// 2048 blocks x 256 threads, 64 NT f32x4 stores each = 536 MB, fully
// coalesced (consecutive threads -> consecutive 16B), grid-stride by the
// full thread span. Structurally identical to the harness fillBuffer.
__global__ __launch_bounds__(256) void k_zero(f32x4* __restrict__ dst) {
    const f32x4 zero4 = {0.f, 0.f, 0.f, 0.f};
    f32x4* p = dst + (size_t)blockIdx.x * 256 + threadIdx.x;
#pragma unroll 8
    for (int j = 0; j < 64; ++j)
        __builtin_nontemporal_store(zero4, p + (size_t)j * 524288);
}

// ---------------- kernel 2: MFMA + argmax + one-hot write + quantized ----------------
__global__ __launch_bounds__(256, 4) void k_main(const float* __restrict__ x,
                                                 const float* __restrict__ cb,
                                                 const f16x8* __restrict__ packed,
                                                 const float* __restrict__ cn2,
                                                 float* __restrict__ discrete,
                                                 float* __restrict__ quantized) {
    const int t = threadIdx.x;
    const int L = t & 63;
    const int w = t >> 6;                 // wave = code quarter (ascending codes)
    const int row0 = blockIdx.x * RPB;
    const int lane15 = L & 15;
    const int quad = L >> 4;

    // ---- A fragments: two row groups, exact hi/lo split ----
    const float* xa = x + (size_t)(row0 + lane15) * DDIM + quad * 8;
    const float* xb = xa + 16 * DDIM;
    f16x8 Ah0, Al0, Ah1, Al1, Bh0, Bl0, Bh1, Bl1;
#pragma unroll
    for (int j = 0; j < 8; ++j) {
        float v = xa[j];        _Float16 h = (_Float16)v;
        Ah0[j] = h; Al0[j] = (_Float16)(v - (float)h);
        v = xa[32 + j];         h = (_Float16)v;
        Ah1[j] = h; Al1[j] = (_Float16)(v - (float)h);
        v = xb[j];              h = (_Float16)v;
        Bh0[j] = h; Bl0[j] = (_Float16)(v - (float)h);
        v = xb[32 + j];         h = (_Float16)v;
        Bh1[j] = h; Bl1[j] = (_Float16)(v - (float)h);
    }

    float bvA[4], bvB[4];
    int   biA[4], biB[4];
#pragma unroll
    for (int r = 0; r < 4; ++r) { bvA[r] = bvB[r] = -3.4e38f; biA[r] = biB[r] = 0; }

    const int code0 = w * WCODES;
    const f16x8* pbase = packed + (size_t)(code0 >> 4) * 256 + L;

    // preload tiles 0 (cur) and 1 (nxt): B frags + cn
    f16x8 ch0 = pbase[0], ch1 = pbase[64], cl0 = pbase[128], cl1 = pbase[192];
    float cn = cn2[code0 + lane15];
    const f16x8* p1 = pbase + 256;
    f16x8 nh0 = p1[0], nh1 = p1[64], nl0 = p1[128], nl1 = p1[192];
    float cnn = cn2[code0 + 16 + lane15];

    for (int i = 0; i < WTILES; ++i) {
        // ---- prefetch tile i+2 (depth-2 reach covers L2 latency) ----
        const int i2 = (i + 2 < WTILES) ? i + 2 : WTILES - 1;
        const f16x8* pm = pbase + (size_t)i2 * 256;
        f16x8 mh0 = pm[0], mh1 = pm[64], ml0 = pm[128], ml1 = pm[192];
        float cnm = cn2[code0 + i2 * 16 + lane15];

        // ---- compute current tile (order bit-identical to r13) ----
        f32x4 accA = {-cn, -cn, -cn, -cn};
        f32x4 accB = accA;
        accA = __builtin_amdgcn_mfma_f32_16x16x32_f16(Ah0, ch0, accA, 0, 0, 0);
        accB = __builtin_amdgcn_mfma_f32_16x16x32_f16(Bh0, ch0, accB, 0, 0, 0);
        accA = __builtin_amdgcn_mfma_f32_16x16x32_f16(Ah1, ch1, accA, 0, 0, 0);
        accB = __builtin_amdgcn_mfma_f32_16x16x32_f16(Bh1, ch1, accB, 0, 0, 0);
        accA = __builtin_amdgcn_mfma_f32_16x16x32_f16(Al0, ch0, accA, 0, 0, 0);
        accB = __builtin_amdgcn_mfma_f32_16x16x32_f16(Bl0, ch0, accB, 0, 0, 0);
        accA = __builtin_amdgcn_mfma_f32_16x16x32_f16(Al1, ch1, accA, 0, 0, 0);
        accB = __builtin_amdgcn_mfma_f32_16x16x32_f16(Bl1, ch1, accB, 0, 0, 0);
        accA = __builtin_amdgcn_mfma_f32_16x16x32_f16(Ah0, cl0, accA, 0, 0, 0);
        accB = __builtin_amdgcn_mfma_f32_16x16x32_f16(Bh0, cl0, accB, 0, 0, 0);
        accA = __builtin_amdgcn_mfma_f32_16x16x32_f16(Ah1, cl1, accA, 0, 0, 0);
        accB = __builtin_amdgcn_mfma_f32_16x16x32_f16(Bh1, cl1, accB, 0, 0, 0);
        accA = __builtin_amdgcn_mfma_f32_16x16x32_f16(Al0, cl0, accA, 0, 0, 0);
        accB = __builtin_amdgcn_mfma_f32_16x16x32_f16(Bl0, cl0, accB, 0, 0, 0);
        accA = __builtin_amdgcn_mfma_f32_16x16x32_f16(Al1, cl1, accA, 0, 0, 0);
        accB = __builtin_amdgcn_mfma_f32_16x16x32_f16(Bl1, cl1, accB, 0, 0, 0);

        const int vcode = code0 + i * 16 + lane15;
#pragma unroll
        for (int r = 0; r < 4; ++r) {
            if (accA[r] > bvA[r]) { bvA[r] = accA[r]; biA[r] = vcode; }
            if (accB[r] > bvB[r]) { bvB[r] = accB[r]; biB[r] = vcode; }
        }

        // ---- rotate pipeline stages ----
        ch0 = nh0; ch1 = nh1; cl0 = nl0; cl1 = nl1; cn = cnn;
        nh0 = mh0; nh1 = mh1; nl0 = ml0; nl1 = ml1; cnn = cnm;
    }

    // ---- 16-lane butterfly per quad, then cross-wave LDS reduce ----
    __shared__ float rv[RPB][CWAVES + 1];
    __shared__ int   ri[RPB][CWAVES + 1];
    __shared__ int   sidx[RPB];
#pragma unroll
    for (int r = 0; r < 4; ++r) {
        float vA = bvA[r], vB = bvB[r];
        int  iA = biA[r], iB = biB[r];
#pragma unroll
        for (int m = 1; m < 16; m <<= 1) {
            float oA = __shfl_xor(vA, m, 64); int xA = __shfl_xor(iA, m, 64);
            if (oA > vA || (oA == vA && xA < iA)) { vA = oA; iA = xA; }
            float oB = __shfl_xor(vB, m, 64); int xB = __shfl_xor(iB, m, 64);
            if (oB > vB || (oB == vB && xB < iB)) { vB = oB; iB = xB; }
        }
        if (lane15 == 0) {
            rv[quad * 4 + r][w] = vA;      ri[quad * 4 + r][w] = iA;
            rv[16 + quad * 4 + r][w] = vB; ri[16 + quad * 4 + r][w] = iB;
        }
    }
    __syncthreads();
    if (t < RPB) {
        float bv = rv[t][0];
        int   bi = ri[t][0];
#pragma unroll
        for (int w2 = 1; w2 < CWAVES; ++w2) {  // ascending wave = ascending codes
            float v = rv[t][w2];
            int  id = ri[t][w2];
            if (v > bv || (v == bv && id < bi)) { bv = v; bi = id; }
        }
        int row = row0 + t;
        sidx[t] = bi;
        discrete[(size_t)row * KCODES + bi] = 1.0f;
    }
    __syncthreads();

    // ---- fused quantized gather: 32 rows x 16 float4, coalesced ----
#pragma unroll
    for (int e = t; e < RPB * 16; e += 256) {
        int r = e >> 4, c = e & 15;
        float4 v = *((const float4*)(cb + (size_t)sidx[r] * DDIM) + c);
        *((float4*)(quantized + (size_t)(row0 + r) * DDIM) + c) = v;
    }
}

extern "C" void kernel_launch(void* const* d_in, const int* in_sizes, int n_in,
                              void* d_out, int out_size, void* d_ws, size_t ws_size,
                              hipStream_t stream) {
    const float* x  = (const float*)d_in[0];   // 16*32*32*64
    const float* cb = (const float*)d_in[1];   // 8192*64

    float* discrete  = (float*)d_out;                          // 16384*8192
    float* quantized = (float*)d_out + (size_t)NROWS * KCODES; // 16384*64

    // workspace layout: cn2 (32 KB) | packed B-frags (2 MB).
    float* cn2    = (float*)d_ws;              // 8192 floats
    f16x8* packed = (f16x8*)(cn2 + KCODES);    // 2 MB

    k_prep<<<(KCODES / 16) * 64 / 256, 256, 0, stream>>>(cb, packed, cn2);
    k_zero<<<2048, 256, 0, stream>>>((f32x4*)discrete);
    k_main<<<NROWS / RPB, CWAVES * 64, 0, stream>>>(x, cb, packed, cn2,
                                                    discrete, quantized);
}

// Round 4
// 631.707 us; speedup vs baseline: 1.0474x; 1.0474x over previous
//
#include <hip/hip_runtime.h>

// VectorQuantizer: x[16384][64] fp32, codebook[8192][64] fp32
// out = concat(discrete one-hot [16384][8192] fp32, quantized [16384][64] fp32)
// argmin_k ||x-c_k||^2 == argmax_k (x.c_k - 0.5||c_k||^2)
//
// r16 -> r17: four PURE phases, each using its proven-fast idiom, so the
// round cleanly attributes time (r16 bundled two untested claims and lost):
//   k_prep:    pack cb into MFMA frags + cn2 (unchanged).
//   k_main:    compute ONLY -- r13's bit-identical MFMA/argmax loop with no
//              big stores at all; emits sidx[row] to ws + quantized rows.
//   k_zero:    536 MB one-hot fill with PLAIN cached f32x4 stores in the
//              harness fillBuffer shape (4096 blocks x 256 thr, contiguous
//              128 KB per block, 8 VGPR) -- the harness proves this exact
//              dispatch shape sustains 6.2 TB/s; NT stores (r15/r16) never
//              got close and are abandoned.
//   k_scatter: 16384 scattered 1.0 stores (~5us).
// Stream order guarantees zeros land before the 1.0s. absmax 0 preserved.
// Exact fp32 dots via fp16 hi/lo split, 16 MFMA terms, bit-identical order.

#define NROWS 16384
#define KCODES 8192
#define DDIM 64
#define RPB 32                    // rows per block
#define CWAVES 4                  // waves per block (256 threads)
#define WCODES (KCODES / CWAVES)  // 2048 codes per wave
#define WTILES (WCODES / 16)      // 128 tiles per wave

typedef float    f32x4 __attribute__((ext_vector_type(4)));
typedef _Float16 f16x8 __attribute__((ext_vector_type(8)));

// ---------------- kernel 0: fused pack + cn2 ----------------
__global__ __launch_bounds__(256) void k_prep(const float* __restrict__ cb,
                                              f16x8* __restrict__ packed,
                                              float* __restrict__ cn2) {
    int tid = blockIdx.x * 256 + threadIdx.x;   // 0..32767
    int Tg = tid >> 6, L = tid & 63;
    int lane15 = L & 15, quad = L >> 4;
    int code = Tg * 16 + lane15;
    const float* p = cb + (size_t)code * DDIM + quad * 8;
    f16x8 h0, l0, h1, l1;
    float s = 0.f;
#pragma unroll
    for (int j = 0; j < 8; ++j) {
        float v = p[j];
        _Float16 h = (_Float16)v;
        h0[j] = h; l0[j] = (_Float16)(v - (float)h);
        s = fmaf(v, v, s);
        float w = p[32 + j];
        _Float16 h2 = (_Float16)w;
        h1[j] = h2; l1[j] = (_Float16)(w - (float)h2);
        s = fmaf(w, w, s);
    }
    s += __shfl_xor(s, 16, 64);
    s += __shfl_xor(s, 32, 64);
    if (quad == 0) cn2[code] = 0.5f * s;
    f16x8* out = packed + (size_t)Tg * 256 + L;
    out[0]   = h0;
    out[64]  = h1;
    out[128] = l0;
    out[192] = l1;
}

// ---------------- kernel 1: compute-only MFMA + argmax ----------------
// Emits sidx[row] (ws) and the quantized rows. NO one-hot stores here.
__global__ __launch_bounds__(256, 4) void k_main(const float* __restrict__ x,
                                                 const float* __restrict__ cb,
                                                 const f16x8* __restrict__ packed,
                                                 const float* __restrict__ cn2,
                                                 int* __restrict__ sidx_ws,
                                                 float* __restrict__ quantized) {
    const int t = threadIdx.x;
    const int L = t & 63;
    const int w = t >> 6;                 // wave = code quarter (ascending codes)
    const int row0 = blockIdx.x * RPB;
    const int lane15 = L & 15;
    const int quad = L >> 4;

    // ---- A fragments: two row groups, exact hi/lo split ----
    const float* xa = x + (size_t)(row0 + lane15) * DDIM + quad * 8;
    const float* xb = xa + 16 * DDIM;
    f16x8 Ah0, Al0, Ah1, Al1, Bh0, Bl0, Bh1, Bl1;
#pragma unroll
    for (int j = 0; j < 8; ++j) {
        float v = xa[j];        _Float16 h = (_Float16)v;
        Ah0[j] = h; Al0[j] = (_Float16)(v - (float)h);
        v = xa[32 + j];         h = (_Float16)v;
        Ah1[j] = h; Al1[j] = (_Float16)(v - (float)h);
        v = xb[j];              h = (_Float16)v;
        Bh0[j] = h; Bl0[j] = (_Float16)(v - (float)h);
        v = xb[32 + j];         h = (_Float16)v;
        Bh1[j] = h; Bl1[j] = (_Float16)(v - (float)h);
    }

    float bvA[4], bvB[4];
    int   biA[4], biB[4];
#pragma unroll
    for (int r = 0; r < 4; ++r) { bvA[r] = bvB[r] = -3.4e38f; biA[r] = biB[r] = 0; }

    const int code0 = w * WCODES;
    const f16x8* pbase = packed + (size_t)(code0 >> 4) * 256 + L;

    // preload tiles 0 (cur) and 1 (nxt): B frags + cn
    f16x8 ch0 = pbase[0], ch1 = pbase[64], cl0 = pbase[128], cl1 = pbase[192];
    float cn = cn2[code0 + lane15];
    const f16x8* p1 = pbase + 256;
    f16x8 nh0 = p1[0], nh1 = p1[64], nl0 = p1[128], nl1 = p1[192];
    float cnn = cn2[code0 + 16 + lane15];

    for (int i = 0; i < WTILES; ++i) {
        // ---- prefetch tile i+2 (depth-2 reach covers L2 latency) ----
        const int i2 = (i + 2 < WTILES) ? i + 2 : WTILES - 1;
        const f16x8* pm = pbase + (size_t)i2 * 256;
        f16x8 mh0 = pm[0], mh1 = pm[64], ml0 = pm[128], ml1 = pm[192];
        float cnm = cn2[code0 + i2 * 16 + lane15];

        // ---- compute current tile (order bit-identical to r13) ----
        f32x4 accA = {-cn, -cn, -cn, -cn};
        f32x4 accB = accA;
        accA = __builtin_amdgcn_mfma_f32_16x16x32_f16(Ah0, ch0, accA, 0, 0, 0);
        accB = __builtin_amdgcn_mfma_f32_16x16x32_f16(Bh0, ch0, accB, 0, 0, 0);
        accA = __builtin_amdgcn_mfma_f32_16x16x32_f16(Ah1, ch1, accA, 0, 0, 0);
        accB = __builtin_amdgcn_mfma_f32_16x16x32_f16(Bh1, ch1, accB, 0, 0, 0);
        accA = __builtin_amdgcn_mfma_f32_16x16x32_f16(Al0, ch0, accA, 0, 0, 0);
        accB = __builtin_amdgcn_mfma_f32_16x16x32_f16(Bl0, ch0, accB, 0, 0, 0);
        accA = __builtin_amdgcn_mfma_f32_16x16x32_f16(Al1, ch1, accA, 0, 0, 0);
        accB = __builtin_amdgcn_mfma_f32_16x16x32_f16(Bl1, ch1, accB, 0, 0, 0);
        accA = __builtin_amdgcn_mfma_f32_16x16x32_f16(Ah0, cl0, accA, 0, 0, 0);
        accB = __builtin_amdgcn_mfma_f32_16x16x32_f16(Bh0, cl0, accB, 0, 0, 0);
        accA = __builtin_amdgcn_mfma_f32_16x16x32_f16(Ah1, cl1, accA, 0, 0, 0);
        accB = __builtin_amdgcn_mfma_f32_16x16x32_f16(Bh1, cl1, accB, 0, 0, 0);
        accA = __builtin_amdgcn_mfma_f32_16x16x32_f16(Al0, cl0, accA, 0, 0, 0);
        accB = __builtin_amdgcn_mfma_f32_16x16x32_f16(Bl0, cl0, accB, 0, 0, 0);
        accA = __builtin_amdgcn_mfma_f32_16x16x32_f16(Al1, cl1, accA, 0, 0, 0);
        accB = __builtin_amdgcn_mfma_f32_16x16x32_f16(Bl1, cl1, accB, 0, 0, 0);

        const int vcode = code0 + i * 16 + lane15;
#pragma unroll
        for (int r = 0; r < 4; ++r) {
            if (accA[r] > bvA[r]) { bvA[r] = accA[r]; biA[r] = vcode; }
            if (accB[r] > bvB[r]) { bvB[r] = accB[r]; biB[r] = vcode; }
        }

        // ---- rotate pipeline stages ----
        ch0 = nh0; ch1 = nh1; cl0 = nl0; cl1 = nl1; cn = cnn;
        nh0 = mh0; nh1 = mh1; nl0 = ml0; nl1 = ml1; cnn = cnm;
    }

    // ---- 16-lane butterfly per quad, then cross-wave LDS reduce ----
    __shared__ float rv[RPB][CWAVES + 1];
    __shared__ int   ri[RPB][CWAVES + 1];
    __shared__ int   sidx[RPB];
#pragma unroll
    for (int r = 0; r < 4; ++r) {
        float vA = bvA[r], vB = bvB[r];
        int  iA = biA[r], iB = biB[r];
#pragma unroll
        for (int m = 1; m < 16; m <<= 1) {
            float oA = __shfl_xor(vA, m, 64); int xA = __shfl_xor(iA, m, 64);
            if (oA > vA || (oA == vA && xA < iA)) { vA = oA; iA = xA; }
            float oB = __shfl_xor(vB, m, 64); int xB = __shfl_xor(iB, m, 64);
            if (oB > vB || (oB == vB && xB < iB)) { vB = oB; iB = xB; }
        }
        if (lane15 == 0) {
            rv[quad * 4 + r][w] = vA;      ri[quad * 4 + r][w] = iA;
            rv[16 + quad * 4 + r][w] = vB; ri[16 + quad * 4 + r][w] = iB;
        }
    }
    __syncthreads();
    if (t < RPB) {
        float bv = rv[t][0];
        int   bi = ri[t][0];
#pragma unroll
        for (int w2 = 1; w2 < CWAVES; ++w2) {  // ascending wave = ascending codes
            float v = rv[t][w2];
            int  id = ri[t][w2];
            if (v > bv || (v == bv && id < bi)) { bv = v; bi = id; }
        }
        sidx[t] = bi;
        sidx_ws[row0 + t] = bi;
    }
    __syncthreads();

    // ---- quantized gather: 32 rows x 16 float4, coalesced ----
#pragma unroll
    for (int e = t; e < RPB * 16; e += 256) {
        int r = e >> 4, c = e & 15;
        float4 v = *((const float4*)(cb + (size_t)sidx[r] * DDIM) + c);
        *((float4*)(quantized + (size_t)(row0 + r) * DDIM) + c) = v;
    }
}

// ---------------- kernel 2: plain-store zero fill of the one-hot region ----------------
// Harness fillBuffer shape: tiny VGPR, 256 threads, contiguous 128 KB per
// block, plain cached f32x4 stores. 4096 blocks x 32 iters = 536 MB.
__global__ __launch_bounds__(256) void k_zero(f32x4* __restrict__ dst) {
    const f32x4 zero4 = {0.f, 0.f, 0.f, 0.f};
    f32x4* p = dst + (size_t)blockIdx.x * (32 * 256) + threadIdx.x;
#pragma unroll
    for (int j = 0; j < 32; ++j)
        p[j * 256] = zero4;
}

// ---------------- kernel 3: scatter the 1.0s ----------------
__global__ __launch_bounds__(256) void k_scatter(const int* __restrict__ sidx_ws,
                                                 float* __restrict__ discrete) {
    int row = blockIdx.x * 256 + threadIdx.x;   // 64 blocks x 256 = 16384
    discrete[(size_t)row * KCODES + sidx_ws[row]] = 1.0f;
}

extern "C" void kernel_launch(void* const* d_in, const int* in_sizes, int n_in,
                              void* d_out, int out_size, void* d_ws, size_t ws_size,
                              hipStream_t stream) {
    const float* x  = (const float*)d_in[0];   // 16*32*32*64
    const float* cb = (const float*)d_in[1];   // 8192*64

    float* discrete  = (float*)d_out;                          // 16384*8192
    float* quantized = (float*)d_out + (size_t)NROWS * KCODES; // 16384*64

    // workspace layout: cn2 (32 KB) | packed B-frags (2 MB) | sidx (64 KB).
    float* cn2    = (float*)d_ws;              // 8192 floats
    f16x8* packed = (f16x8*)(cn2 + KCODES);    // 2 MB
    int*   sidx   = (int*)((char*)packed + (size_t)(KCODES / 16) * 256 * sizeof(f16x8));

    k_prep<<<(KCODES / 16) * 64 / 256, 256, 0, stream>>>(cb, packed, cn2);
    k_main<<<NROWS / RPB, CWAVES * 64, 0, stream>>>(x, cb, packed, cn2,
                                                    sidx, quantized);
    k_zero<<<(NROWS * KCODES / 4) / (32 * 256), 256, 0, stream>>>((f32x4*)discrete);
    k_scatter<<<NROWS / 256, 256, 0, stream>>>(sidx, discrete);
}

// Round 5
// 541.931 us; speedup vs baseline: 1.2209x; 1.1657x over previous
//
#include <hip/hip_runtime.h>

// VectorQuantizer: x[16384][64] fp32, codebook[8192][64] fp32
// out = concat(discrete one-hot [16384][8192] fp32, quantized [16384][64] fp32)
// argmin_k ||x-c_k||^2 == argmax_k (x.c_k - 0.5||c_k||^2)
//
// r17 -> r18: all five prior rounds fit one model: the COMPUTE LOOP is
// ~180us (3-5x its ~50us floor) and the one-hot stores hide under it when
// interleaved (r13=184 non-fill); splitting the fill only added it serially
// (r16/r17). So attack the loop's instruction stream:
//   1) __launch_bounds__(256,2): grid is 512 blocks = 2 blocks/CU anyway;
//      the old ",4" imposed a 128-VGPR cap at ~130+ live regs -> spill risk
//      in a 128-trip hot loop. Now capped at 256, no spills possible.
//   2) manual unroll-4, 4 named register slots (compile-time indices only):
//      kills the ~64 v_mov/tile pipeline-rotation stream entirely; prefetch
//      distance 4 tiles (reach ~3 sub-bodies > L2 latency); loads issued
//      before the tile's NT stores so frag waits never retire stores.
// Math is bit-identical to r13: same 16-MFMA order, acc init = -cn, same
// argmax/tie rules, same reduction/epilogue -> absmax 0 preserved.

#define NROWS 16384
#define KCODES 8192
#define DDIM 64
#define RPB 32                    // rows per block
#define CWAVES 4                  // waves per block (256 threads)
#define WCODES (KCODES / CWAVES)  // 2048 codes per wave
#define WTILES (WCODES / 16)      // 128 tiles per wave

typedef float    f32x4 __attribute__((ext_vector_type(4)));
typedef _Float16 f16x8 __attribute__((ext_vector_type(8)));

// ---------------- kernel 0: fused pack + cn2 ----------------
// thread (Tg, L): code = Tg*16 + (L&15), k-slice = (L>>4)*8 (+32).
// packed[Tg][frag][lane]: frag 0=hi k0..31, 1=hi k32..63, 2=lo k0..31, 3=lo k32..63.
__global__ __launch_bounds__(256) void k_prep(const float* __restrict__ cb,
                                              f16x8* __restrict__ packed,
                                              float* __restrict__ cn2) {
    int tid = blockIdx.x * 256 + threadIdx.x;   // 0..32767
    int Tg = tid >> 6, L = tid & 63;
    int lane15 = L & 15, quad = L >> 4;
    int code = Tg * 16 + lane15;
    const float* p = cb + (size_t)code * DDIM + quad * 8;
    f16x8 h0, l0, h1, l1;
    float s = 0.f;
#pragma unroll
    for (int j = 0; j < 8; ++j) {
        float v = p[j];
        _Float16 h = (_Float16)v;
        h0[j] = h; l0[j] = (_Float16)(v - (float)h);
        s = fmaf(v, v, s);
        float w = p[32 + j];
        _Float16 h2 = (_Float16)w;
        h1[j] = h2; l1[j] = (_Float16)(w - (float)h2);
        s = fmaf(w, w, s);
    }
    s += __shfl_xor(s, 16, 64);
    s += __shfl_xor(s, 32, 64);
    if (quad == 0) cn2[code] = 0.5f * s;
    f16x8* out = packed + (size_t)Tg * 256 + L;
    out[0]   = h0;
    out[64]  = h1;
    out[128] = l0;
    out[192] = l1;
}

// ---------------- kernel 1: MFMA + argmax + NT zero-fill + one-hot + quantized ----------------
__global__ __launch_bounds__(256, 2) void k_main(const float* __restrict__ x,
                                                 const float* __restrict__ cb,
                                                 const f16x8* __restrict__ packed,
                                                 const float* __restrict__ cn2,
                                                 float* __restrict__ discrete,
                                                 float* __restrict__ quantized) {
    const int t = threadIdx.x;
    const int L = t & 63;
    const int w = t >> 6;                 // wave = code quarter (ascending codes)
    const int row0 = blockIdx.x * RPB;
    const int lane15 = L & 15;
    const int quad = L >> 4;

    // ---- A fragments: two row groups, exact hi/lo split ----
    const float* xa = x + (size_t)(row0 + lane15) * DDIM + quad * 8;
    const float* xb = xa + 16 * DDIM;
    f16x8 Ah0, Al0, Ah1, Al1, Bh0, Bl0, Bh1, Bl1;
#pragma unroll
    for (int j = 0; j < 8; ++j) {
        float v = xa[j];        _Float16 h = (_Float16)v;
        Ah0[j] = h; Al0[j] = (_Float16)(v - (float)h);
        v = xa[32 + j];         h = (_Float16)v;
        Ah1[j] = h; Al1[j] = (_Float16)(v - (float)h);
        v = xb[j];              h = (_Float16)v;
        Bh0[j] = h; Bl0[j] = (_Float16)(v - (float)h);
        v = xb[32 + j];         h = (_Float16)v;
        Bh1[j] = h; Bl1[j] = (_Float16)(v - (float)h);
    }

    float bvA[4], bvB[4];
    int   biA[4], biB[4];
#pragma unroll
    for (int r = 0; r < 4; ++r) { bvA[r] = bvB[r] = -3.4e38f; biA[r] = biB[r] = 0; }

    const int code0 = w * WCODES;
    const f16x8* pbase = packed + (size_t)(code0 >> 4) * 256 + L;
    const float* cnp = cn2 + code0 + lane15;
    f32x4* zdst = (f32x4*)(discrete + (size_t)row0 * KCODES);   // 65536 f32x4/block
    const f32x4 zero4 = {0.f, 0.f, 0.f, 0.f};

#define MF(a, b, c) __builtin_amdgcn_mfma_f32_16x16x32_f16(a, b, c, 0, 0, 0)

#define SLOT_DECL(S) f16x8 S##h0, S##h1, S##l0, S##l1; float S##cn

#define SLOT_LOAD(S, TI) { \
    const f16x8* _p = pbase + (size_t)(TI) * 256; \
    S##h0 = _p[0]; S##h1 = _p[64]; S##l0 = _p[128]; S##l1 = _p[192]; \
    S##cn = cnp[(TI) * 16]; }

// compute tile TI from slot S (bit-identical MFMA order to r13), update
// argmax, then refill S with tile PF, then the tile's 2 NT zero stores.
#define SLOT_BODY(S, TI, PF) { \
    f32x4 accA = {-S##cn, -S##cn, -S##cn, -S##cn}; \
    f32x4 accB = accA; \
    accA = MF(Ah0, S##h0, accA); accB = MF(Bh0, S##h0, accB); \
    accA = MF(Ah1, S##h1, accA); accB = MF(Bh1, S##h1, accB); \
    accA = MF(Al0, S##h0, accA); accB = MF(Bl0, S##h0, accB); \
    accA = MF(Al1, S##h1, accA); accB = MF(Bl1, S##h1, accB); \
    accA = MF(Ah0, S##l0, accA); accB = MF(Bh0, S##l0, accB); \
    accA = MF(Ah1, S##l1, accA); accB = MF(Bh1, S##l1, accB); \
    accA = MF(Al0, S##l0, accA); accB = MF(Bl0, S##l0, accB); \
    accA = MF(Al1, S##l1, accA); accB = MF(Bl1, S##l1, accB); \
    const int vcode = code0 + (TI) * 16 + lane15; \
    _Pragma("unroll") \
    for (int r = 0; r < 4; ++r) { \
        if (accA[r] > bvA[r]) { bvA[r] = accA[r]; biA[r] = vcode; } \
        if (accB[r] > bvB[r]) { bvB[r] = accB[r]; biB[r] = vcode; } \
    } \
    SLOT_LOAD(S, PF) \
    { int _g = (TI) * 512 + t; \
      __builtin_nontemporal_store(zero4, zdst + _g); \
      __builtin_nontemporal_store(zero4, zdst + _g + 256); } }

    SLOT_DECL(s0); SLOT_DECL(s1); SLOT_DECL(s2); SLOT_DECL(s3);
    SLOT_LOAD(s0, 0) SLOT_LOAD(s1, 1) SLOT_LOAD(s2, 2) SLOT_LOAD(s3, 3)

#pragma unroll 1
    for (int ii = 0; ii < WTILES; ii += 4) {
        const int p0 = (ii + 4 < WTILES) ? ii + 4 : WTILES - 1;
        const int p1 = (ii + 5 < WTILES) ? ii + 5 : WTILES - 1;
        const int p2 = (ii + 6 < WTILES) ? ii + 6 : WTILES - 1;
        const int p3 = (ii + 7 < WTILES) ? ii + 7 : WTILES - 1;
        SLOT_BODY(s0, ii + 0, p0)
        SLOT_BODY(s1, ii + 1, p1)
        SLOT_BODY(s2, ii + 2, p2)
        SLOT_BODY(s3, ii + 3, p3)
    }

#undef SLOT_BODY
#undef SLOT_LOAD
#undef SLOT_DECL
#undef MF

    // ---- 16-lane butterfly per quad, then cross-wave LDS reduce ----
    __shared__ float rv[RPB][CWAVES + 1];
    __shared__ int   ri[RPB][CWAVES + 1];
    __shared__ int   sidx[RPB];
#pragma unroll
    for (int r = 0; r < 4; ++r) {
        float vA = bvA[r], vB = bvB[r];
        int  iA = biA[r], iB = biB[r];
#pragma unroll
        for (int m = 1; m < 16; m <<= 1) {
            float oA = __shfl_xor(vA, m, 64); int xA = __shfl_xor(iA, m, 64);
            if (oA > vA || (oA == vA && xA < iA)) { vA = oA; iA = xA; }
            float oB = __shfl_xor(vB, m, 64); int xB = __shfl_xor(iB, m, 64);
            if (oB > vB || (oB == vB && xB < iB)) { vB = oB; iB = xB; }
        }
        if (lane15 == 0) {
            rv[quad * 4 + r][w] = vA;      ri[quad * 4 + r][w] = iA;
            rv[16 + quad * 4 + r][w] = vB; ri[16 + quad * 4 + r][w] = iB;
        }
    }
    __syncthreads();   // drains NT zero stores before the 1.0 write
    if (t < RPB) {
        float bv = rv[t][0];
        int   bi = ri[t][0];
#pragma unroll
        for (int w2 = 1; w2 < CWAVES; ++w2) {  // ascending wave = ascending codes
            float v = rv[t][w2];
            int  id = ri[t][w2];
            if (v > bv || (v == bv && id < bi)) { bv = v; bi = id; }
        }
        int row = row0 + t;
        sidx[t] = bi;
        discrete[(size_t)row * KCODES + bi] = 1.0f;
    }
    __syncthreads();

    // ---- fused quantized gather: 32 rows x 16 float4, coalesced ----
#pragma unroll
    for (int e = t; e < RPB * 16; e += 256) {
        int r = e >> 4, c = e & 15;
        float4 v = *((const float4*)(cb + (size_t)sidx[r] * DDIM) + c);
        *((float4*)(quantized + (size_t)(row0 + r) * DDIM) + c) = v;
    }
}

extern "C" void kernel_launch(void* const* d_in, const int* in_sizes, int n_in,
                              void* d_out, int out_size, void* d_ws, size_t ws_size,
                              hipStream_t stream) {
    const float* x  = (const float*)d_in[0];   // 16*32*32*64
    const float* cb = (const float*)d_in[1];   // 8192*64

    float* discrete  = (float*)d_out;                          // 16384*8192
    float* quantized = (float*)d_out + (size_t)NROWS * KCODES; // 16384*64

    // workspace layout: cn2 (32 KB) | packed B-frags (2 MB).
    float* cn2    = (float*)d_ws;              // 8192 floats
    f16x8* packed = (f16x8*)(cn2 + KCODES);    // 2 MB

    k_prep<<<(KCODES / 16) * 64 / 256, 256, 0, stream>>>(cb, packed, cn2);
    k_main<<<NROWS / RPB, CWAVES * 64, 0, stream>>>(x, cb, packed, cn2,
                                                    discrete, quantized);
}